// Round 12
// baseline (259.834 us; speedup 1.0000x reference)
//
#include <hip/hip_runtime.h>
#include <hip/hip_fp16.h>

typedef float v2f __attribute__((ext_vector_type(2)));

// ---------------- problem constants ----------------
#define NN    1024
#define CC    128
#define NELEM 10
#define NQ3   816
#define NQ2   136
#define NQ    968
#define KP    48     // unified p-dim: 30 (w3) + 12 (w2) + 4 (w1) + 2 pad
#define QT    11     // q-tile per fold block (88 tiles per e)
#define NTILE 88

// ---------------- workspace layout (bytes) ----------------
#define NL_OFF    0          // int[10][1024] = 40960
#define CNT_OFF   40960      // int[10]
#define CALL_OFF  524288     // uint2[1280][968] = 9912320 -> 10436608
#define UHAT_OFF  10485760   // float[4][968][48] = 743424
#define F_OFF     20447232   // float4[1024][128] = 2097152 -> 22544384

__device__ __constant__ int d_OFF2[16] = {0,16,31,45,58,70,81,91,100,108,115,121,126,130,133,135};
__device__ __constant__ int d_OFF3[16] = {0,136,256,361,452,530,596,651,696,732,760,781,796,806,812,815};

// ---- setup: blocks 0..63 = sym3, 64..68 = sym2+linear, 69 = species lists ----
__global__ void k_setup(const float* __restrict__ U3_0, const float* __restrict__ U3_1,
                        const float* __restrict__ U2_0, const float* __restrict__ U2_1,
                        const float* __restrict__ U1_0, const float* __restrict__ U1_1,
                        const int* __restrict__ species,
                        float* __restrict__ uhat, int* __restrict__ nodelist,
                        int* __restrict__ counts) {
    if (blockIdx.x < 64) {
        int tid = blockIdx.x * 256 + threadIdx.x;
        int Lout = tid >> 12;
        int r = tid & 4095;
        int a = r >> 8, b = (r >> 4) & 15, m = r & 15;
        if (a > b || b > m) return;
        int q = d_OFF3[a] + (d_OFF2[b] - d_OFF2[a]) + (m - b);
        const float* U = (Lout == 0) ? U3_0 : U3_1;
        int L = (Lout == 0) ? 0 : (Lout - 1);
        int P[6][3] = {{a,b,m},{a,m,b},{b,a,m},{b,m,a},{m,a,b},{m,b,a}};
        float s[30];
#pragma unroll
        for (int p = 0; p < 30; ++p) s[p] = 0.f;
        for (int t = 0; t < 6; ++t) {
            bool dup = false;
            for (int u = 0; u < t; ++u)
                if (P[u][0] == P[t][0] && P[u][1] == P[t][1] && P[u][2] == P[t][2]) dup = true;
            if (dup) continue;
            const float* src = U + ((((L * 16 + P[t][0]) * 16 + P[t][1]) * 16 + P[t][2]) * 30);
#pragma unroll
            for (int p = 0; p < 30; ++p) s[p] += src[p];
        }
        float* dst = uhat + ((size_t)Lout * NQ + q) * KP;
#pragma unroll
        for (int p = 0; p < 30; ++p) dst[p] = s[p];
#pragma unroll
        for (int p = 30; p < KP; ++p) dst[p] = 0.f;
    } else if (blockIdx.x < 69) {
        int tid = (blockIdx.x - 64) * 256 + threadIdx.x;
        if (tid < 1024) {
            int Lout = tid >> 8;
            int r = tid & 255;
            int a = r >> 4, b = r & 15;
            if (a > b) return;
            int q = NQ3 + d_OFF2[a] + (b - a);
            const float* U = (Lout == 0) ? U2_0 : U2_1;
            int L = (Lout == 0) ? 0 : (Lout - 1);
            float* dst = uhat + ((size_t)Lout * NQ + q) * KP;
#pragma unroll
            for (int p = 0; p < 30; ++p) dst[p] = 0.f;
#pragma unroll
            for (int p = 0; p < 12; ++p) {
                float v = U[((L * 16 + a) * 16 + b) * 12 + p];
                if (a != b) v += U[((L * 16 + b) * 16 + a) * 12 + p];
                dst[30 + p] = v;
            }
#pragma unroll
            for (int p = 42; p < KP; ++p) dst[p] = 0.f;
        } else if (tid < 1024 + 64) {
            int s2 = tid - 1024;
            int Lout = s2 >> 4, i = s2 & 15;
            int q = NQ3 + NQ2 + i;
            const float* U = (Lout == 0) ? U1_0 : U1_1;
            int L = (Lout == 0) ? 0 : (Lout - 1);
            float* dst = uhat + ((size_t)Lout * NQ + q) * KP;
#pragma unroll
            for (int p = 0; p < 42; ++p) dst[p] = 0.f;
#pragma unroll
            for (int p = 0; p < 4; ++p) dst[42 + p] = U[(L * 16 + i) * 4 + p];
            dst[46] = 0.f; dst[47] = 0.f;
        }
    } else {
        __shared__ int cnt[NELEM];
        int t = threadIdx.x;
        if (t < NELEM) cnt[t] = 0;
        __syncthreads();
#pragma unroll
        for (int j = 0; j < 4; ++j) {
            int node = t * 4 + j;
            int e = species[node];
            int pos = atomicAdd(&cnt[e], 1);
            nodelist[e * NN + pos] = node;
        }
        __syncthreads();
        if (t < NELEM) counts[t] = cnt[t];
    }
}

// ---- fold: call4h[ec][q] = half4{ dot48(Uhat[L][q][:], Wcat[Lg][:]) } ----
__global__ __launch_bounds__(256) void k_fold(
    const float* __restrict__ uhat,
    const float* __restrict__ W1_0, const float* __restrict__ W2_0, const float* __restrict__ W3_0,
    const float* __restrict__ W1_1, const float* __restrict__ W2_1, const float* __restrict__ W3_1,
    uint2* __restrict__ call4h) {
    __shared__ __align__(16) float uh_lds[4][QT][KP];   // 8448 B
    int e  = blockIdx.x / NTILE;
    int qt = blockIdx.x % NTILE;
    int t = threadIdx.x;
    {
        const float4* src4 = (const float4*)uhat;
        float4* dst4 = (float4*)uh_lds;
        for (int i = t; i < 4 * QT * 12; i += 256) {
            int l = i / (QT * 12);
            int r = i - l * (QT * 12);
            int qloc = r / 12, p4 = r % 12;
            dst4[i] = src4[((size_t)l * NQ + qt * QT + qloc) * 12 + p4];
        }
    }
    int c  = t & 127;
    int qs = t >> 7;
    float wr[2][KP];
#pragma unroll
    for (int p = 0; p < 30; ++p) {
        wr[0][p] = W3_0[(e * 30 + p) * CC + c];
        wr[1][p] = W3_1[(e * 30 + p) * CC + c];
    }
#pragma unroll
    for (int p = 0; p < 12; ++p) {
        wr[0][30 + p] = W2_0[(e * 12 + p) * CC + c];
        wr[1][30 + p] = W2_1[(e * 12 + p) * CC + c];
    }
#pragma unroll
    for (int p = 0; p < 4; ++p) {
        wr[0][42 + p] = W1_0[(e * 4 + p) * CC + c];
        wr[1][42 + p] = W1_1[(e * 4 + p) * CC + c];
    }
    wr[0][46] = wr[0][47] = wr[1][46] = wr[1][47] = 0.f;
    __syncthreads();
    size_t base = ((size_t)e * CC + c) * NQ;
    for (int j = 0; j < 6; ++j) {
        int qloc = qs * 6 + j;
        if (qloc >= QT) break;
        int q = qt * QT + qloc;
        float r[4];
#pragma unroll
        for (int l = 0; l < 4; ++l) {
            const float4* up = (const float4*)uh_lds[l][qloc];
            const float* w = (l == 0) ? wr[0] : wr[1];
            float acc0 = 0.f, acc1 = 0.f, acc2 = 0.f, acc3 = 0.f;
#pragma unroll
            for (int p4 = 0; p4 < 12; ++p4) {
                float4 u = up[p4];
                acc0 = fmaf(u.x, w[p4 * 4 + 0], acc0);
                acc1 = fmaf(u.y, w[p4 * 4 + 1], acc1);
                acc2 = fmaf(u.z, w[p4 * 4 + 2], acc2);
                acc3 = fmaf(u.w, w[p4 * 4 + 3], acc3);
            }
            r[l] = (acc0 + acc1) + (acc2 + acc3);
        }
        __half2 h01 = __floats2half2_rn(r[0], r[1]);
        __half2 h23 = __floats2half2_rn(r[2], r[3]);
        uint2 v;
        v.x = *(unsigned int*)&h01;
        v.y = *(unsigned int*)&h23;
        call4h[base + q] = v;
    }
}

// ---- monomial macros: f16 coeff unpack + pk-fp32 fma (wave-private LDS table) ----
#define COEF(W0, W1, W2, W3) \
    uint2 pk = cf[q]; \
    __half2 h01 = *(__half2*)&pk.x; __half2 h23 = *(__half2*)&pk.y; \
    float W0 = __half2float(h01.x), W1 = __half2float(h01.y); \
    float W2 = __half2float(h23.x), W3 = __half2float(h23.y);

#define CUBIC(A0, A1) { \
    _Pragma("unroll") for (int a = (A0); a < (A1); ++a) { \
        _Pragma("unroll") for (int b = a; b < 16; ++b) { \
            v2f pab = xv[a] * xv[b]; \
            _Pragma("unroll") for (int m = b; m < 16; ++m) { \
                COEF(wx, wy, wz, ww); v2f mo = pab * xv[m]; \
                a0 += mo * wx; a1 += mo * wy; a2 += mo * wz; a3 += mo * ww; ++q; } } } }

#define QUAD(A0, A1) { \
    _Pragma("unroll") for (int a = (A0); a < (A1); ++a) { \
        _Pragma("unroll") for (int b = a; b < 16; ++b) { \
            COEF(wx, wy, wz, ww); v2f mo = xv[a] * xv[b]; \
            a0 += mo * wx; a1 += mo * wy; a2 += mo * wz; a3 += mo * ww; ++q; } } }

// ---- polynomial eval: ONE (e,c) PER WAVE. No __syncthreads, no q-slicing:
// ---- every wave runs the identical full-968 body (shared I$ path), stages its
// ---- own 7.7KB f16 coeff table (wave-private; same-wave ds ordering suffices).
__global__ __launch_bounds__(128, 2) void k_eval(
    const float* __restrict__ x, const int* __restrict__ nodelist,
    const int* __restrict__ counts, const uint2* __restrict__ call4h,
    float4* __restrict__ fout) {
    __shared__ __align__(16) uint2 cf16[2][NQ];      // 15488 B (per-wave halves)
    int t = threadIdx.x;
    int widx = t >> 6, lane = t & 63;
    int ec = blockIdx.x * 2 + widx;                  // 640 blocks x 2 waves = 1280
    int e = ec >> 7, c = ec & 127;
    int cnt = counts[e];
    const uint2* src = call4h + (size_t)ec * NQ;
    uint2* cf = cf16[widx];

    // wave-private stage: coalesced 8B loads; no barrier needed
    for (int i = lane; i < NQ; i += 64) cf[i] = src[i];

    for (int sb = 0; sb < cnt; sb += 128) {
        int i0 = sb + lane * 2, i1 = i0 + 1;
        bool v0i = i0 < cnt, v1i = i1 < cnt;
        int n0 = v0i ? nodelist[e * NN + i0] : 0;
        int n1 = v1i ? nodelist[e * NN + i1] : 0;
        const float4* xp0 = (const float4*)(x + ((size_t)n0 * CC + c) * 16);
        const float4* xp1 = (const float4*)(x + ((size_t)n1 * CC + c) * 16);
        float4 p0 = xp0[0], p1 = xp0[1], p2 = xp0[2], p3 = xp0[3];
        float4 q0 = xp1[0], q1 = xp1[1], q2 = xp1[2], q3 = xp1[3];
        v2f xv[16];
        xv[0]  = v2f{p0.x, q0.x}; xv[1]  = v2f{p0.y, q0.y};
        xv[2]  = v2f{p0.z, q0.z}; xv[3]  = v2f{p0.w, q0.w};
        xv[4]  = v2f{p1.x, q1.x}; xv[5]  = v2f{p1.y, q1.y};
        xv[6]  = v2f{p1.z, q1.z}; xv[7]  = v2f{p1.w, q1.w};
        xv[8]  = v2f{p2.x, q2.x}; xv[9]  = v2f{p2.y, q2.y};
        xv[10] = v2f{p2.z, q2.z}; xv[11] = v2f{p2.w, q2.w};
        xv[12] = v2f{p3.x, q3.x}; xv[13] = v2f{p3.y, q3.y};
        xv[14] = v2f{p3.z, q3.z}; xv[15] = v2f{p3.w, q3.w};
        if (!v0i) {
#pragma unroll
            for (int m = 0; m < 16; ++m) xv[m].x = 0.f;
        }
        if (!v1i) {
#pragma unroll
            for (int m = 0; m < 16; ++m) xv[m].y = 0.f;
        }
        v2f a0 = {0.f, 0.f}, a1 = {0.f, 0.f}, a2 = {0.f, 0.f}, a3 = {0.f, 0.f};
        int q = 0;
        CUBIC(0, 16);                 // q 0..815
        QUAD(0, 16);                  // q 816..951
#pragma unroll
        for (int a = 0; a < 16; ++a) {  // linear: q 952..967
            COEF(wx, wy, wz, ww); v2f mo = xv[a];
            a0 += mo * wx; a1 += mo * wy; a2 += mo * wz; a3 += mo * ww; ++q;
        }
        if (v0i) fout[(size_t)n0 * CC + c] = make_float4(a0.x, a1.x, a2.x, a3.x);
        if (v1i) fout[(size_t)n1 * CC + c] = make_float4(a0.y, a1.y, a2.y, a3.y);
    }
}

// ---- epilogue linear: 4 nodes per block ----
__global__ __launch_bounds__(256) void k_linear(
    const float4* __restrict__ fin, const float* __restrict__ Wlin0,
    const float* __restrict__ Wlin1, float* __restrict__ out) {
    __shared__ float4 fl[512];
    int t = threadIdx.x;
    fl[t]       = fin[(size_t)blockIdx.x * 512 + t];
    fl[t + 256] = fin[(size_t)blockIdx.x * 512 + t + 256];
    __syncthreads();
    int nh = t >> 7, k = t & 127;
    int n = blockIdx.x * 4 + nh * 2;
    float a0 = 0.f, a1 = 0.f, a2 = 0.f, a3 = 0.f;
    float b0 = 0.f, b1 = 0.f, b2 = 0.f, b3 = 0.f;
#pragma unroll 8
    for (int c = 0; c < CC; ++c) {
        float4 f0 = fl[(nh * 2) * CC + c];
        float4 f1 = fl[(nh * 2 + 1) * CC + c];
        float w0 = Wlin0[c * CC + k];
        float w1 = Wlin1[c * CC + k];
        a0 = fmaf(f0.x, w0, a0); a1 = fmaf(f0.y, w1, a1);
        a2 = fmaf(f0.z, w1, a2); a3 = fmaf(f0.w, w1, a3);
        b0 = fmaf(f1.x, w0, b0); b1 = fmaf(f1.y, w1, b1);
        b2 = fmaf(f1.z, w1, b2); b3 = fmaf(f1.w, w1, b3);
    }
    const float s = 0.08838834764831845f; // 1/sqrt(128)
    float* o = out + (size_t)n * 512;
    o[k] = a0 * s;
    o[128 + 3 * k + 0] = a1 * s;
    o[128 + 3 * k + 1] = a2 * s;
    o[128 + 3 * k + 2] = a3 * s;
    o += 512;
    o[k] = b0 * s;
    o[128 + 3 * k + 0] = b1 * s;
    o[128 + 3 * k + 1] = b2 * s;
    o[128 + 3 * k + 2] = b3 * s;
}

extern "C" void kernel_launch(void* const* d_in, const int* in_sizes, int n_in,
                              void* d_out, int out_size, void* d_ws, size_t ws_size,
                              hipStream_t stream) {
    const float* x     = (const float*)d_in[0];
    const int*   spec  = (const int*)d_in[1];
    const float* U1_0  = (const float*)d_in[2];
    const float* U2_0  = (const float*)d_in[3];
    const float* U3_0  = (const float*)d_in[4];
    const float* W1_0  = (const float*)d_in[5];
    const float* W2_0  = (const float*)d_in[6];
    const float* W3_0  = (const float*)d_in[7];
    const float* Wl_0  = (const float*)d_in[8];
    const float* U1_1  = (const float*)d_in[9];
    const float* U2_1  = (const float*)d_in[10];
    const float* U3_1  = (const float*)d_in[11];
    const float* W1_1  = (const float*)d_in[12];
    const float* W2_1  = (const float*)d_in[13];
    const float* W3_1  = (const float*)d_in[14];
    const float* Wl_1  = (const float*)d_in[15];

    char* ws = (char*)d_ws;
    int*    nodelist = (int*)(ws + NL_OFF);
    int*    counts   = (int*)(ws + CNT_OFF);
    uint2*  call4h   = (uint2*)(ws + CALL_OFF);
    float*  uhat     = (float*)(ws + UHAT_OFF);
    float4* fbuf     = (float4*)(ws + F_OFF);

    k_setup<<<dim3(70), dim3(256), 0, stream>>>(U3_0, U3_1, U2_0, U2_1, U1_0, U1_1,
                                                spec, uhat, nodelist, counts);
    k_fold<<<dim3(880), dim3(256), 0, stream>>>(uhat, W1_0, W2_0, W3_0,
                                                W1_1, W2_1, W3_1, call4h);
    k_eval<<<dim3(640), dim3(128), 0, stream>>>(x, nodelist, counts, call4h, fbuf);
    k_linear<<<dim3(256), dim3(256), 0, stream>>>(fbuf, Wl_0, Wl_1, (float*)d_out);
}

// Round 13
// 198.872 us; speedup vs baseline: 1.3065x; 1.3065x over previous
//
#include <hip/hip_runtime.h>
#include <hip/hip_fp16.h>

typedef float v2f __attribute__((ext_vector_type(2)));

// ---------------- problem constants ----------------
#define NN    1024
#define CC    128
#define NELEM 10
#define NQ3   816
#define NQ2   136
#define NQ    968
#define KP    48     // unified p-dim: 30 (w3) + 12 (w2) + 4 (w1) + 2 pad
#define QT    11     // q-tile per fold block (88 tiles per e)
#define NTILE 88

// ---------------- workspace layout (bytes) ----------------
#define NL_OFF    0          // int[10][1024] = 40960
#define CNT_OFF   40960      // int[10]
#define CALL_OFF  524288     // uint2[1280][968] = 9912320 -> 10436608
#define UHAT_OFF  10485760   // float[4][968][48] = 743424
#define F0_OFF    20447232   // float4[1024][128] = 2097152
#define F1_OFF    22544384   // float4[1024][128] = 2097152 -> 24641536

__device__ __constant__ int d_OFF2[16] = {0,16,31,45,58,70,81,91,100,108,115,121,126,130,133,135};
__device__ __constant__ int d_OFF3[16] = {0,136,256,361,452,530,596,651,696,732,760,781,796,806,812,815};

// ---- setup: blocks 0..63 = sym3, 64..68 = sym2+linear, 69 = species lists ----
__global__ void k_setup(const float* __restrict__ U3_0, const float* __restrict__ U3_1,
                        const float* __restrict__ U2_0, const float* __restrict__ U2_1,
                        const float* __restrict__ U1_0, const float* __restrict__ U1_1,
                        const int* __restrict__ species,
                        float* __restrict__ uhat, int* __restrict__ nodelist,
                        int* __restrict__ counts) {
    if (blockIdx.x < 64) {
        int tid = blockIdx.x * 256 + threadIdx.x;
        int Lout = tid >> 12;
        int r = tid & 4095;
        int a = r >> 8, b = (r >> 4) & 15, m = r & 15;
        if (a > b || b > m) return;
        int q = d_OFF3[a] + (d_OFF2[b] - d_OFF2[a]) + (m - b);
        const float* U = (Lout == 0) ? U3_0 : U3_1;
        int L = (Lout == 0) ? 0 : (Lout - 1);
        int P[6][3] = {{a,b,m},{a,m,b},{b,a,m},{b,m,a},{m,a,b},{m,b,a}};
        float s[30];
#pragma unroll
        for (int p = 0; p < 30; ++p) s[p] = 0.f;
        for (int t = 0; t < 6; ++t) {
            bool dup = false;
            for (int u = 0; u < t; ++u)
                if (P[u][0] == P[t][0] && P[u][1] == P[t][1] && P[u][2] == P[t][2]) dup = true;
            if (dup) continue;
            const float* src = U + ((((L * 16 + P[t][0]) * 16 + P[t][1]) * 16 + P[t][2]) * 30);
#pragma unroll
            for (int p = 0; p < 30; ++p) s[p] += src[p];
        }
        float* dst = uhat + ((size_t)Lout * NQ + q) * KP;
#pragma unroll
        for (int p = 0; p < 30; ++p) dst[p] = s[p];
#pragma unroll
        for (int p = 30; p < KP; ++p) dst[p] = 0.f;
    } else if (blockIdx.x < 69) {
        int tid = (blockIdx.x - 64) * 256 + threadIdx.x;
        if (tid < 1024) {
            int Lout = tid >> 8;
            int r = tid & 255;
            int a = r >> 4, b = r & 15;
            if (a > b) return;
            int q = NQ3 + d_OFF2[a] + (b - a);
            const float* U = (Lout == 0) ? U2_0 : U2_1;
            int L = (Lout == 0) ? 0 : (Lout - 1);
            float* dst = uhat + ((size_t)Lout * NQ + q) * KP;
#pragma unroll
            for (int p = 0; p < 30; ++p) dst[p] = 0.f;
#pragma unroll
            for (int p = 0; p < 12; ++p) {
                float v = U[((L * 16 + a) * 16 + b) * 12 + p];
                if (a != b) v += U[((L * 16 + b) * 16 + a) * 12 + p];
                dst[30 + p] = v;
            }
#pragma unroll
            for (int p = 42; p < KP; ++p) dst[p] = 0.f;
        } else if (tid < 1024 + 64) {
            int s2 = tid - 1024;
            int Lout = s2 >> 4, i = s2 & 15;
            int q = NQ3 + NQ2 + i;
            const float* U = (Lout == 0) ? U1_0 : U1_1;
            int L = (Lout == 0) ? 0 : (Lout - 1);
            float* dst = uhat + ((size_t)Lout * NQ + q) * KP;
#pragma unroll
            for (int p = 0; p < 42; ++p) dst[p] = 0.f;
#pragma unroll
            for (int p = 0; p < 4; ++p) dst[42 + p] = U[(L * 16 + i) * 4 + p];
            dst[46] = 0.f; dst[47] = 0.f;
        }
    } else {
        __shared__ int cnt[NELEM];
        int t = threadIdx.x;
        if (t < NELEM) cnt[t] = 0;
        __syncthreads();
#pragma unroll
        for (int j = 0; j < 4; ++j) {
            int node = t * 4 + j;
            int e = species[node];
            int pos = atomicAdd(&cnt[e], 1);
            nodelist[e * NN + pos] = node;
        }
        __syncthreads();
        if (t < NELEM) counts[t] = cnt[t];
    }
}

// ---- fold: call4h[ec][q] = half4{ dot48(Uhat[L][q][:], Wcat[Lg][:]) } ----
__global__ __launch_bounds__(256) void k_fold(
    const float* __restrict__ uhat,
    const float* __restrict__ W1_0, const float* __restrict__ W2_0, const float* __restrict__ W3_0,
    const float* __restrict__ W1_1, const float* __restrict__ W2_1, const float* __restrict__ W3_1,
    uint2* __restrict__ call4h) {
    __shared__ __align__(16) float uh_lds[4][QT][KP];   // 8448 B
    int e  = blockIdx.x / NTILE;
    int qt = blockIdx.x % NTILE;
    int t = threadIdx.x;
    {
        const float4* src4 = (const float4*)uhat;
        float4* dst4 = (float4*)uh_lds;
        for (int i = t; i < 4 * QT * 12; i += 256) {
            int l = i / (QT * 12);
            int r = i - l * (QT * 12);
            int qloc = r / 12, p4 = r % 12;
            dst4[i] = src4[((size_t)l * NQ + qt * QT + qloc) * 12 + p4];
        }
    }
    int c  = t & 127;
    int qs = t >> 7;
    float wr[2][KP];
#pragma unroll
    for (int p = 0; p < 30; ++p) {
        wr[0][p] = W3_0[(e * 30 + p) * CC + c];
        wr[1][p] = W3_1[(e * 30 + p) * CC + c];
    }
#pragma unroll
    for (int p = 0; p < 12; ++p) {
        wr[0][30 + p] = W2_0[(e * 12 + p) * CC + c];
        wr[1][30 + p] = W2_1[(e * 12 + p) * CC + c];
    }
#pragma unroll
    for (int p = 0; p < 4; ++p) {
        wr[0][42 + p] = W1_0[(e * 4 + p) * CC + c];
        wr[1][42 + p] = W1_1[(e * 4 + p) * CC + c];
    }
    wr[0][46] = wr[0][47] = wr[1][46] = wr[1][47] = 0.f;
    __syncthreads();
    size_t base = ((size_t)e * CC + c) * NQ;
    for (int j = 0; j < 6; ++j) {
        int qloc = qs * 6 + j;
        if (qloc >= QT) break;
        int q = qt * QT + qloc;
        float r[4];
#pragma unroll
        for (int l = 0; l < 4; ++l) {
            const float4* up = (const float4*)uh_lds[l][qloc];
            const float* w = (l == 0) ? wr[0] : wr[1];
            float acc0 = 0.f, acc1 = 0.f, acc2 = 0.f, acc3 = 0.f;
#pragma unroll
            for (int p4 = 0; p4 < 12; ++p4) {
                float4 u = up[p4];
                acc0 = fmaf(u.x, w[p4 * 4 + 0], acc0);
                acc1 = fmaf(u.y, w[p4 * 4 + 1], acc1);
                acc2 = fmaf(u.z, w[p4 * 4 + 2], acc2);
                acc3 = fmaf(u.w, w[p4 * 4 + 3], acc3);
            }
            r[l] = (acc0 + acc1) + (acc2 + acc3);
        }
        __half2 h01 = __floats2half2_rn(r[0], r[1]);
        __half2 h23 = __floats2half2_rn(r[2], r[3]);
        uint2 v;
        v.x = *(unsigned int*)&h01;
        v.y = *(unsigned int*)&h23;
        call4h[base + q] = v;
    }
}

// ---- monomial macros: f16 coeff unpack + pk-fp32 fma ----
#define COEF(W0, W1, W2, W3) \
    uint2 pk = cf_lds[q]; \
    __half2 h01 = *(__half2*)&pk.x; __half2 h23 = *(__half2*)&pk.y; \
    float W0 = __half2float(h01.x), W1 = __half2float(h01.y); \
    float W2 = __half2float(h23.x), W3 = __half2float(h23.y);

#define CUBIC(A0, A1) { \
    _Pragma("unroll") for (int a = (A0); a < (A1); ++a) { \
        _Pragma("unroll") for (int b = a; b < 16; ++b) { \
            v2f pab = xv[a] * xv[b]; \
            _Pragma("unroll") for (int m = b; m < 16; ++m) { \
                COEF(wx, wy, wz, ww); v2f mo = pab * xv[m]; \
                a0 += mo * wx; a1 += mo * wy; a2 += mo * wz; a3 += mo * ww; ++q; } } } }

#define QUAD(A0, A1) { \
    _Pragma("unroll") for (int a = (A0); a < (A1); ++a) { \
        _Pragma("unroll") for (int b = a; b < 16; ++b) { \
            COEF(wx, wy, wz, ww); v2f mo = xv[a] * xv[b]; \
            a0 += mo * wx; a1 += mo * wy; a2 += mo * wz; a3 += mo * ww; ++q; } } }

// ---- polynomial eval: 2560 blocks = (e,c) x 2 halves; 4 wave-slices each
// ---- (8 q-slices total per (e,c)); 2 nodes/thread; partials to fb0/fb1 ----
__global__ __launch_bounds__(256) void k_eval(
    const float* __restrict__ x, const int* __restrict__ nodelist,
    const int* __restrict__ counts, const uint2* __restrict__ call4h,
    float4* __restrict__ fb0, float4* __restrict__ fb1) {
    __shared__ __align__(16) uint2 cf_lds[NQ];       // 7744 B
    __shared__ __align__(16) v2f part[3][64][4];     // 6144 B
    int ec = blockIdx.x >> 1;
    int h  = blockIdx.x & 1;
    int e = ec >> 7;
    int c = ec & 127;
    int cnt = counts[e];
    const uint2* src = call4h + (size_t)ec * NQ;
    float4* fb = h ? fb1 : fb0;
    int t = threadIdx.x;
    int slice = t >> 6;
    int lane  = t & 63;

    // first-batch node ids issued before staging (vmem overlap)
    int i0 = lane * 2, i1 = i0 + 1;
    bool v0i = i0 < cnt, v1i = i1 < cnt;
    int n0 = v0i ? nodelist[e * NN + i0] : 0;
    int n1 = v1i ? nodelist[e * NN + i1] : 0;

    // stage full f16 table (coalesced 8B)
    for (int i = t; i < NQ; i += 256) cf_lds[i] = src[i];

    for (int sb = 0; sb < cnt; sb += 128) {
        if (sb > 0) {
            i0 = sb + lane * 2; i1 = i0 + 1;
            v0i = i0 < cnt; v1i = i1 < cnt;
            n0 = v0i ? nodelist[e * NN + i0] : 0;
            n1 = v1i ? nodelist[e * NN + i1] : 0;
        }
        const float4* xp0 = (const float4*)(x + ((size_t)n0 * CC + c) * 16);
        const float4* xp1 = (const float4*)(x + ((size_t)n1 * CC + c) * 16);
        float4 p0 = xp0[0], p1 = xp0[1], p2 = xp0[2], p3 = xp0[3];
        float4 q0 = xp1[0], q1 = xp1[1], q2 = xp1[2], q3 = xp1[3];
        if (sb == 0) __syncthreads();   // staging visible before cf_lds reads
        v2f xv[16];
        xv[0]  = v2f{p0.x, q0.x}; xv[1]  = v2f{p0.y, q0.y};
        xv[2]  = v2f{p0.z, q0.z}; xv[3]  = v2f{p0.w, q0.w};
        xv[4]  = v2f{p1.x, q1.x}; xv[5]  = v2f{p1.y, q1.y};
        xv[6]  = v2f{p1.z, q1.z}; xv[7]  = v2f{p1.w, q1.w};
        xv[8]  = v2f{p2.x, q2.x}; xv[9]  = v2f{p2.y, q2.y};
        xv[10] = v2f{p2.z, q2.z}; xv[11] = v2f{p2.w, q2.w};
        xv[12] = v2f{p3.x, q3.x}; xv[13] = v2f{p3.y, q3.y};
        xv[14] = v2f{p3.z, q3.z}; xv[15] = v2f{p3.w, q3.w};
        if (!v0i) {
#pragma unroll
            for (int m = 0; m < 16; ++m) xv[m].x = 0.f;
        }
        if (!v1i) {
#pragma unroll
            for (int m = 0; m < 16; ++m) xv[m].y = 0.f;
        }
        v2f a0 = {0.f, 0.f}, a1 = {0.f, 0.f}, a2 = {0.f, 0.f}, a3 = {0.f, 0.f};
        int q;
        if (h == 0) {
            if (slice == 0)      { q = 0;   CUBIC(0, 1); }            // 136
            else if (slice == 1) { q = 136; CUBIC(1, 2); }            // 120
            else if (slice == 2) { q = 256; CUBIC(2, 3); }            // 105
            else                 { q = 361; CUBIC(3, 4);              // 91
                                   q = NQ3; QUAD(0, 2); }             // +31
        } else {
            if (slice == 0)      { q = 452; CUBIC(4, 6); }            // 144
            else if (slice == 1) { q = 596; CUBIC(6, 9); }            // 136
            else if (slice == 2) { q = 732; CUBIC(9, 16);             // 84
                                   q = NQ3 + 31; QUAD(2, 5); }        // +39
            else                 { q = NQ3 + 70; QUAD(5, 16);         // 66
                                   q = NQ3 + NQ2;                     // +16 linear
#pragma unroll
                                   for (int a = 0; a < 16; ++a) {
                                       COEF(wx, wy, wz, ww); v2f mo = xv[a];
                                       a0 += mo * wx; a1 += mo * wy;
                                       a2 += mo * wz; a3 += mo * ww; ++q;
                                   } }
        }
        if (slice > 0) {
            part[slice - 1][lane][0] = a0; part[slice - 1][lane][1] = a1;
            part[slice - 1][lane][2] = a2; part[slice - 1][lane][3] = a3;
        }
        __syncthreads();
        if (slice == 0) {
            v2f s0 = a0 + part[0][lane][0] + part[1][lane][0] + part[2][lane][0];
            v2f s1 = a1 + part[0][lane][1] + part[1][lane][1] + part[2][lane][1];
            v2f s2 = a2 + part[0][lane][2] + part[1][lane][2] + part[2][lane][2];
            v2f s3 = a3 + part[0][lane][3] + part[1][lane][3] + part[2][lane][3];
            if (v0i) fb[(size_t)n0 * CC + c] = make_float4(s0.x, s1.x, s2.x, s3.x);
            if (v1i) fb[(size_t)n1 * CC + c] = make_float4(s0.y, s1.y, s2.y, s3.y);
        }
        __syncthreads();
    }
}

// ---- epilogue linear: 4 nodes per block; sums the two eval halves ----
__global__ __launch_bounds__(256) void k_linear(
    const float4* __restrict__ f0in, const float4* __restrict__ f1in,
    const float* __restrict__ Wlin0, const float* __restrict__ Wlin1,
    float* __restrict__ out) {
    __shared__ float4 fl[512];
    int t = threadIdx.x;
    {
        float4 u0 = f0in[(size_t)blockIdx.x * 512 + t];
        float4 u1 = f1in[(size_t)blockIdx.x * 512 + t];
        fl[t] = make_float4(u0.x + u1.x, u0.y + u1.y, u0.z + u1.z, u0.w + u1.w);
        float4 w0 = f0in[(size_t)blockIdx.x * 512 + t + 256];
        float4 w1 = f1in[(size_t)blockIdx.x * 512 + t + 256];
        fl[t + 256] = make_float4(w0.x + w1.x, w0.y + w1.y, w0.z + w1.z, w0.w + w1.w);
    }
    __syncthreads();
    int nh = t >> 7, k = t & 127;
    int n = blockIdx.x * 4 + nh * 2;
    float a0 = 0.f, a1 = 0.f, a2 = 0.f, a3 = 0.f;
    float b0 = 0.f, b1 = 0.f, b2 = 0.f, b3 = 0.f;
#pragma unroll 8
    for (int c = 0; c < CC; ++c) {
        float4 f0 = fl[(nh * 2) * CC + c];
        float4 f1 = fl[(nh * 2 + 1) * CC + c];
        float w0 = Wlin0[c * CC + k];
        float w1 = Wlin1[c * CC + k];
        a0 = fmaf(f0.x, w0, a0); a1 = fmaf(f0.y, w1, a1);
        a2 = fmaf(f0.z, w1, a2); a3 = fmaf(f0.w, w1, a3);
        b0 = fmaf(f1.x, w0, b0); b1 = fmaf(f1.y, w1, b1);
        b2 = fmaf(f1.z, w1, b2); b3 = fmaf(f1.w, w1, b3);
    }
    const float s = 0.08838834764831845f; // 1/sqrt(128)
    float* o = out + (size_t)n * 512;
    o[k] = a0 * s;
    o[128 + 3 * k + 0] = a1 * s;
    o[128 + 3 * k + 1] = a2 * s;
    o[128 + 3 * k + 2] = a3 * s;
    o += 512;
    o[k] = b0 * s;
    o[128 + 3 * k + 0] = b1 * s;
    o[128 + 3 * k + 1] = b2 * s;
    o[128 + 3 * k + 2] = b3 * s;
}

extern "C" void kernel_launch(void* const* d_in, const int* in_sizes, int n_in,
                              void* d_out, int out_size, void* d_ws, size_t ws_size,
                              hipStream_t stream) {
    const float* x     = (const float*)d_in[0];
    const int*   spec  = (const int*)d_in[1];
    const float* U1_0  = (const float*)d_in[2];
    const float* U2_0  = (const float*)d_in[3];
    const float* U3_0  = (const float*)d_in[4];
    const float* W1_0  = (const float*)d_in[5];
    const float* W2_0  = (const float*)d_in[6];
    const float* W3_0  = (const float*)d_in[7];
    const float* Wl_0  = (const float*)d_in[8];
    const float* U1_1  = (const float*)d_in[9];
    const float* U2_1  = (const float*)d_in[10];
    const float* U3_1  = (const float*)d_in[11];
    const float* W1_1  = (const float*)d_in[12];
    const float* W2_1  = (const float*)d_in[13];
    const float* W3_1  = (const float*)d_in[14];
    const float* Wl_1  = (const float*)d_in[15];

    char* ws = (char*)d_ws;
    int*    nodelist = (int*)(ws + NL_OFF);
    int*    counts   = (int*)(ws + CNT_OFF);
    uint2*  call4h   = (uint2*)(ws + CALL_OFF);
    float*  uhat     = (float*)(ws + UHAT_OFF);
    float4* fbuf0    = (float4*)(ws + F0_OFF);
    float4* fbuf1    = (float4*)(ws + F1_OFF);

    k_setup<<<dim3(70), dim3(256), 0, stream>>>(U3_0, U3_1, U2_0, U2_1, U1_0, U1_1,
                                                spec, uhat, nodelist, counts);
    k_fold<<<dim3(880), dim3(256), 0, stream>>>(uhat, W1_0, W2_0, W3_0,
                                                W1_1, W2_1, W3_1, call4h);
    k_eval<<<dim3(2560), dim3(256), 0, stream>>>(x, nodelist, counts, call4h,
                                                 fbuf0, fbuf1);
    k_linear<<<dim3(256), dim3(256), 0, stream>>>(fbuf0, fbuf1, Wl_0, Wl_1,
                                                  (float*)d_out);
}

// Round 14
// 76.863 us; speedup vs baseline: 3.3805x; 2.5873x over previous
//
#include <hip/hip_runtime.h>
#include <hip/hip_fp16.h>

typedef float v2f __attribute__((ext_vector_type(2)));
typedef _Float16 h2f __attribute__((ext_vector_type(2)));

static __device__ __forceinline__ h2f as_h2(unsigned int u) {
    union { unsigned int i; h2f h; } x; x.i = u; return x.h;
}
static __device__ __forceinline__ float dot2f(h2f a, h2f b, float c) {
#if __has_builtin(__builtin_amdgcn_fdot2)
    return __builtin_amdgcn_fdot2(a, b, c, false);
#else
    return c + (float)a.x * (float)b.x + (float)a.y * (float)b.y;
#endif
}

// ---------------- problem constants ----------------
#define NN    1024
#define CC    128
#define NELEM 10
#define NQ3   816
#define NQ2   136
#define NQ    968
#define KP    48     // unified p-dim: 30 (w3) + 12 (w2) + 4 (w1) + 2 pad
#define QT    11     // q-tile per fold block (88 tiles per e)
#define NTILE 88

// ---------------- workspace layout (bytes) ----------------
#define NL_OFF    0          // int[10][1024] = 40960
#define CNT_OFF   40960      // int[10]
#define CALL_OFF  524288     // half4[1280][968] = 9912320 -> 10436608
#define UHAT_OFF  10485760   // __half[4][968][48] = 371712
#define F_OFF     20447232   // float4[1024][128] = 2097152 -> 22544384

__device__ __constant__ int d_OFF2[16] = {0,16,31,45,58,70,81,91,100,108,115,121,126,130,133,135};
__device__ __constant__ int d_OFF3[16] = {0,136,256,361,452,530,596,651,696,732,760,781,796,806,812,815};

// ---- setup: blocks 0..63 = sym3, 64..68 = sym2+linear, 69 = species lists ----
__global__ void k_setup(const float* __restrict__ U3_0, const float* __restrict__ U3_1,
                        const float* __restrict__ U2_0, const float* __restrict__ U2_1,
                        const float* __restrict__ U1_0, const float* __restrict__ U1_1,
                        const int* __restrict__ species,
                        __half* __restrict__ uhat, int* __restrict__ nodelist,
                        int* __restrict__ counts) {
    if (blockIdx.x < 64) {
        int tid = blockIdx.x * 256 + threadIdx.x;
        int Lout = tid >> 12;
        int r = tid & 4095;
        int a = r >> 8, b = (r >> 4) & 15, m = r & 15;
        if (a > b || b > m) return;
        int q = d_OFF3[a] + (d_OFF2[b] - d_OFF2[a]) + (m - b);
        const float* U = (Lout == 0) ? U3_0 : U3_1;
        int L = (Lout == 0) ? 0 : (Lout - 1);
        int P[6][3] = {{a,b,m},{a,m,b},{b,a,m},{b,m,a},{m,a,b},{m,b,a}};
        float s[30];
#pragma unroll
        for (int p = 0; p < 30; ++p) s[p] = 0.f;
        for (int t = 0; t < 6; ++t) {
            bool dup = false;
            for (int u = 0; u < t; ++u)
                if (P[u][0] == P[t][0] && P[u][1] == P[t][1] && P[u][2] == P[t][2]) dup = true;
            if (dup) continue;
            const float* src = U + ((((L * 16 + P[t][0]) * 16 + P[t][1]) * 16 + P[t][2]) * 30);
#pragma unroll
            for (int p = 0; p < 30; ++p) s[p] += src[p];
        }
        __half* dst = uhat + ((size_t)Lout * NQ + q) * KP;
#pragma unroll
        for (int p = 0; p < 30; ++p) dst[p] = __float2half(s[p]);
#pragma unroll
        for (int p = 30; p < KP; ++p) dst[p] = __float2half(0.f);
    } else if (blockIdx.x < 69) {
        int tid = (blockIdx.x - 64) * 256 + threadIdx.x;
        if (tid < 1024) {
            int Lout = tid >> 8;
            int r = tid & 255;
            int a = r >> 4, b = r & 15;
            if (a > b) return;
            int q = NQ3 + d_OFF2[a] + (b - a);
            const float* U = (Lout == 0) ? U2_0 : U2_1;
            int L = (Lout == 0) ? 0 : (Lout - 1);
            __half* dst = uhat + ((size_t)Lout * NQ + q) * KP;
#pragma unroll
            for (int p = 0; p < 30; ++p) dst[p] = __float2half(0.f);
#pragma unroll
            for (int p = 0; p < 12; ++p) {
                float v = U[((L * 16 + a) * 16 + b) * 12 + p];
                if (a != b) v += U[((L * 16 + b) * 16 + a) * 12 + p];
                dst[30 + p] = __float2half(v);
            }
#pragma unroll
            for (int p = 42; p < KP; ++p) dst[p] = __float2half(0.f);
        } else if (tid < 1024 + 64) {
            int s2 = tid - 1024;
            int Lout = s2 >> 4, i = s2 & 15;
            int q = NQ3 + NQ2 + i;
            const float* U = (Lout == 0) ? U1_0 : U1_1;
            int L = (Lout == 0) ? 0 : (Lout - 1);
            __half* dst = uhat + ((size_t)Lout * NQ + q) * KP;
#pragma unroll
            for (int p = 0; p < 42; ++p) dst[p] = __float2half(0.f);
#pragma unroll
            for (int p = 0; p < 4; ++p) dst[42 + p] = __float2half(U[(L * 16 + i) * 4 + p]);
            dst[46] = __float2half(0.f); dst[47] = __float2half(0.f);
        }
    } else {
        __shared__ int cnt[NELEM];
        int t = threadIdx.x;
        if (t < NELEM) cnt[t] = 0;
        __syncthreads();
#pragma unroll
        for (int j = 0; j < 4; ++j) {
            int node = t * 4 + j;
            int e = species[node];
            int pos = atomicAdd(&cnt[e], 1);
            nodelist[e * NN + pos] = node;
        }
        __syncthreads();
        if (t < NELEM) counts[t] = cnt[t];
    }
}

// ---- fold: call4h[ec][q] = half4{ dot48_f16(Uhat[L][q][:], Wcat[Lg][:]) } ----
// uhat is f16: 264 ds_read_b128 + 96 v_dot2_f32_f16 per 4L-q (halved LDS + VALU)
__global__ __launch_bounds__(256) void k_fold(
    const __half* __restrict__ uhat,
    const float* __restrict__ W1_0, const float* __restrict__ W2_0, const float* __restrict__ W3_0,
    const float* __restrict__ W1_1, const float* __restrict__ W2_1, const float* __restrict__ W3_1,
    uint2* __restrict__ call4h) {
    __shared__ __align__(16) __half uh_lds[4][QT][KP];   // 4224 B
    int e  = blockIdx.x / NTILE;
    int qt = blockIdx.x % NTILE;
    int t = threadIdx.x;
    // stage Uhat tile: 4L x QT x 6 uint4 (8 halves each) = 264 uint4, coalesced
    {
        const uint4* src4 = (const uint4*)uhat;
        uint4* dst4 = (uint4*)uh_lds;
        for (int i = t; i < 4 * QT * 6; i += 256) {
            int l = i / (QT * 6);
            int r = i - l * (QT * 6);
            int qloc = r / 6, p4 = r % 6;
            dst4[i] = src4[((size_t)l * NQ + qt * QT + qloc) * 6 + p4];
        }
    }
    int c  = t & 127;
    int qs = t >> 7;
    // W in f16x2 registers: 2 groups x 24 h2 (48 values each)
    float wf[2][KP];
#pragma unroll
    for (int p = 0; p < 30; ++p) {
        wf[0][p] = W3_0[(e * 30 + p) * CC + c];
        wf[1][p] = W3_1[(e * 30 + p) * CC + c];
    }
#pragma unroll
    for (int p = 0; p < 12; ++p) {
        wf[0][30 + p] = W2_0[(e * 12 + p) * CC + c];
        wf[1][30 + p] = W2_1[(e * 12 + p) * CC + c];
    }
#pragma unroll
    for (int p = 0; p < 4; ++p) {
        wf[0][42 + p] = W1_0[(e * 4 + p) * CC + c];
        wf[1][42 + p] = W1_1[(e * 4 + p) * CC + c];
    }
    wf[0][46] = wf[0][47] = wf[1][46] = wf[1][47] = 0.f;
    h2f wh[2][KP / 2];
#pragma unroll
    for (int g = 0; g < 2; ++g)
#pragma unroll
        for (int j = 0; j < KP / 2; ++j) {
            h2f h; h.x = (_Float16)wf[g][2 * j]; h.y = (_Float16)wf[g][2 * j + 1];
            wh[g][j] = h;
        }
    __syncthreads();
    size_t base = ((size_t)e * CC + c) * NQ;
    for (int j = 0; j < 6; ++j) {
        int qloc = qs * 6 + j;
        if (qloc >= QT) break;
        int q = qt * QT + qloc;
        float r[4];
#pragma unroll
        for (int l = 0; l < 4; ++l) {
            const uint4* up = (const uint4*)&uh_lds[l][qloc][0];
            int g = (l == 0) ? 0 : 1;
            float acc = 0.f;
#pragma unroll
            for (int p4 = 0; p4 < 6; ++p4) {
                uint4 u = up[p4];
                acc = dot2f(as_h2(u.x), wh[g][p4 * 4 + 0], acc);
                acc = dot2f(as_h2(u.y), wh[g][p4 * 4 + 1], acc);
                acc = dot2f(as_h2(u.z), wh[g][p4 * 4 + 2], acc);
                acc = dot2f(as_h2(u.w), wh[g][p4 * 4 + 3], acc);
            }
            r[l] = acc;
        }
        __half2 h01 = __floats2half2_rn(r[0], r[1]);
        __half2 h23 = __floats2half2_rn(r[2], r[3]);
        uint2 v;
        v.x = *(unsigned int*)&h01;
        v.y = *(unsigned int*)&h23;
        call4h[base + q] = v;
    }
}

// ---- monomial macros: f32 coeffs from LDS; 4 nodes (2 v2f pairs) per lane ----
#define CUBIC(A0, A1) { \
    _Pragma("unroll") for (int a = (A0); a < (A1); ++a) { \
        _Pragma("unroll") for (int b = a; b < 16; ++b) { \
            v2f pabA = xvA[a] * xvA[b]; v2f pabB = xvB[a] * xvB[b]; \
            _Pragma("unroll") for (int m = b; m < 16; ++m) { \
                float4 w = cfp[q]; \
                v2f moA = pabA * xvA[m]; v2f moB = pabB * xvB[m]; \
                aA0 += moA * w.x; aA1 += moA * w.y; aA2 += moA * w.z; aA3 += moA * w.w; \
                aB0 += moB * w.x; aB1 += moB * w.y; aB2 += moB * w.z; aB3 += moB * w.w; \
                ++q; } } } }

#define QUAD(A0, A1) { \
    _Pragma("unroll") for (int a = (A0); a < (A1); ++a) { \
        _Pragma("unroll") for (int b = a; b < 16; ++b) { \
            float4 w = cfp[q]; \
            v2f moA = xvA[a] * xvA[b]; v2f moB = xvB[a] * xvB[b]; \
            aA0 += moA * w.x; aA1 += moA * w.y; aA2 += moA * w.z; aA3 += moA * w.w; \
            aB0 += moB * w.x; aB1 += moB * w.y; aB2 += moB * w.z; aB3 += moB * w.w; \
            ++q; } } }

// ---- polynomial eval (R6 champion, byte-identical): block=(e, 2 channels);
// ---- 4 q-slice waves; half-wave = channel; 4 nodes per lane ----
__global__ void k_eval(
    const float* __restrict__ x, const int* __restrict__ nodelist,
    const int* __restrict__ counts, const uint2* __restrict__ call4h,
    float4* __restrict__ fout) {
    __shared__ __align__(16) float4 cf_lds[2][NQ + 2];   // 31040 B
    __shared__ __align__(16) v2f part[3][64][9];         // 13824 B
    int blk = blockIdx.x;            // 640 = 10 e x 64 c-pairs
    int e  = blk >> 6;
    int c0 = (blk & 63) * 2;
    int cnt = counts[e];
    int t = threadIdx.x;
    int slice = t >> 6, lane = t & 63;
    int half = lane >> 5, ls = lane & 31;
    int c = c0 + half;

    // stage + upconvert coefficients for both channels (coalesced uint2)
    const uint2* src = call4h + ((size_t)e * CC + c0) * NQ;
    for (int i = t; i < 2 * NQ; i += 256) {
        uint2 pk = src[i];
        __half2 h01 = *(__half2*)&pk.x, h23 = *(__half2*)&pk.y;
        int ch = i >= NQ;
        cf_lds[ch][i - ch * NQ] = make_float4(
            __half2float(h01.x), __half2float(h01.y),
            __half2float(h23.x), __half2float(h23.y));
    }
    __syncthreads();
    const float4* cfp = cf_lds[half];

    for (int sb = 0; sb < cnt; sb += 128) {
        int ib = sb + ls * 4;
        bool v0 = ib < cnt, v1 = ib + 1 < cnt, v2 = ib + 2 < cnt, v3 = ib + 3 < cnt;
        int n0 = v0 ? nodelist[e * NN + ib] : 0;
        int n1 = v1 ? nodelist[e * NN + ib + 1] : 0;
        int n2 = v2 ? nodelist[e * NN + ib + 2] : 0;
        int n3 = v3 ? nodelist[e * NN + ib + 3] : 0;
        const float4* xp0 = (const float4*)(x + ((size_t)n0 * CC + c) * 16);
        const float4* xp1 = (const float4*)(x + ((size_t)n1 * CC + c) * 16);
        const float4* xp2 = (const float4*)(x + ((size_t)n2 * CC + c) * 16);
        const float4* xp3 = (const float4*)(x + ((size_t)n3 * CC + c) * 16);
        float4 r0, r1, r2, r3, s0, s1, s2, s3;
        v2f xvA[16], xvB[16];
        r0 = xp0[0]; r1 = xp0[1]; r2 = xp0[2]; r3 = xp0[3];
        s0 = xp1[0]; s1 = xp1[1]; s2 = xp1[2]; s3 = xp1[3];
        xvA[0]  = v2f{r0.x, s0.x}; xvA[1]  = v2f{r0.y, s0.y};
        xvA[2]  = v2f{r0.z, s0.z}; xvA[3]  = v2f{r0.w, s0.w};
        xvA[4]  = v2f{r1.x, s1.x}; xvA[5]  = v2f{r1.y, s1.y};
        xvA[6]  = v2f{r1.z, s1.z}; xvA[7]  = v2f{r1.w, s1.w};
        xvA[8]  = v2f{r2.x, s2.x}; xvA[9]  = v2f{r2.y, s2.y};
        xvA[10] = v2f{r2.z, s2.z}; xvA[11] = v2f{r2.w, s2.w};
        xvA[12] = v2f{r3.x, s3.x}; xvA[13] = v2f{r3.y, s3.y};
        xvA[14] = v2f{r3.z, s3.z}; xvA[15] = v2f{r3.w, s3.w};
        r0 = xp2[0]; r1 = xp2[1]; r2 = xp2[2]; r3 = xp2[3];
        s0 = xp3[0]; s1 = xp3[1]; s2 = xp3[2]; s3 = xp3[3];
        xvB[0]  = v2f{r0.x, s0.x}; xvB[1]  = v2f{r0.y, s0.y};
        xvB[2]  = v2f{r0.z, s0.z}; xvB[3]  = v2f{r0.w, s0.w};
        xvB[4]  = v2f{r1.x, s1.x}; xvB[5]  = v2f{r1.y, s1.y};
        xvB[6]  = v2f{r1.z, s1.z}; xvB[7]  = v2f{r1.w, s1.w};
        xvB[8]  = v2f{r2.x, s2.x}; xvB[9]  = v2f{r2.y, s2.y};
        xvB[10] = v2f{r2.z, s2.z}; xvB[11] = v2f{r2.w, s2.w};
        xvB[12] = v2f{r3.x, s3.x}; xvB[13] = v2f{r3.y, s3.y};
        xvB[14] = v2f{r3.z, s3.z}; xvB[15] = v2f{r3.w, s3.w};
        if (!v0) {
#pragma unroll
            for (int m = 0; m < 16; ++m) xvA[m].x = 0.f;
        }
        if (!v1) {
#pragma unroll
            for (int m = 0; m < 16; ++m) xvA[m].y = 0.f;
        }
        if (!v2) {
#pragma unroll
            for (int m = 0; m < 16; ++m) xvB[m].x = 0.f;
        }
        if (!v3) {
#pragma unroll
            for (int m = 0; m < 16; ++m) xvB[m].y = 0.f;
        }
        v2f aA0 = {0.f,0.f}, aA1 = {0.f,0.f}, aA2 = {0.f,0.f}, aA3 = {0.f,0.f};
        v2f aB0 = {0.f,0.f}, aB1 = {0.f,0.f}, aB2 = {0.f,0.f}, aB3 = {0.f,0.f};
        int q;
        if (slice == 0) {            // cubic a=0..1                           (256)
            q = 0;   CUBIC(0, 2);
        } else if (slice == 1) {     // cubic a=2..3 + quad a=0..3             (254)
            q = 256; CUBIC(2, 4);
            q = NQ3; QUAD(0, 4);
        } else if (slice == 2) {     // cubic a=4..6 + quad a=4..9             (256)
            q = 452; CUBIC(4, 7);
            q = NQ3 + 58; QUAD(4, 10);
        } else {                     // cubic a=7..15 + quad a=10..15 + linear (202)
            q = 651; CUBIC(7, 16);
            q = NQ3 + 115; QUAD(10, 16);
            q = NQ3 + NQ2;
#pragma unroll
            for (int a = 0; a < 16; ++a) {
                float4 w = cfp[q];
                v2f moA = xvA[a], moB = xvB[a];
                aA0 += moA * w.x; aA1 += moA * w.y; aA2 += moA * w.z; aA3 += moA * w.w;
                aB0 += moB * w.x; aB1 += moB * w.y; aB2 += moB * w.z; aB3 += moB * w.w;
                ++q;
            }
        }
        if (slice > 0) {
            v2f* pp = part[slice - 1][lane];
            pp[0] = aA0; pp[1] = aA1; pp[2] = aA2; pp[3] = aA3;
            pp[4] = aB0; pp[5] = aB1; pp[6] = aB2; pp[7] = aB3;
        }
        __syncthreads();
        if (slice == 0) {
            v2f sA0 = aA0 + part[0][lane][0] + part[1][lane][0] + part[2][lane][0];
            v2f sA1 = aA1 + part[0][lane][1] + part[1][lane][1] + part[2][lane][1];
            v2f sA2 = aA2 + part[0][lane][2] + part[1][lane][2] + part[2][lane][2];
            v2f sA3 = aA3 + part[0][lane][3] + part[1][lane][3] + part[2][lane][3];
            v2f sB0 = aB0 + part[0][lane][4] + part[1][lane][4] + part[2][lane][4];
            v2f sB1 = aB1 + part[0][lane][5] + part[1][lane][5] + part[2][lane][5];
            v2f sB2 = aB2 + part[0][lane][6] + part[1][lane][6] + part[2][lane][6];
            v2f sB3 = aB3 + part[0][lane][7] + part[1][lane][7] + part[2][lane][7];
            if (v0) fout[(size_t)n0 * CC + c] = make_float4(sA0.x, sA1.x, sA2.x, sA3.x);
            if (v1) fout[(size_t)n1 * CC + c] = make_float4(sA0.y, sA1.y, sA2.y, sA3.y);
            if (v2) fout[(size_t)n2 * CC + c] = make_float4(sB0.x, sB1.x, sB2.x, sB3.x);
            if (v3) fout[(size_t)n3 * CC + c] = make_float4(sB0.y, sB1.y, sB2.y, sB3.y);
        }
        __syncthreads();
    }
}

// ---- epilogue linear: 4 nodes per block ----
__global__ __launch_bounds__(256) void k_linear(
    const float4* __restrict__ fin, const float* __restrict__ Wlin0,
    const float* __restrict__ Wlin1, float* __restrict__ out) {
    __shared__ float4 fl[512];
    int t = threadIdx.x;
    fl[t]       = fin[(size_t)blockIdx.x * 512 + t];
    fl[t + 256] = fin[(size_t)blockIdx.x * 512 + t + 256];
    __syncthreads();
    int nh = t >> 7, k = t & 127;
    int n = blockIdx.x * 4 + nh * 2;
    float a0 = 0.f, a1 = 0.f, a2 = 0.f, a3 = 0.f;
    float b0 = 0.f, b1 = 0.f, b2 = 0.f, b3 = 0.f;
#pragma unroll 8
    for (int c = 0; c < CC; ++c) {
        float4 f0 = fl[(nh * 2) * CC + c];
        float4 f1 = fl[(nh * 2 + 1) * CC + c];
        float w0 = Wlin0[c * CC + k];
        float w1 = Wlin1[c * CC + k];
        a0 = fmaf(f0.x, w0, a0); a1 = fmaf(f0.y, w1, a1);
        a2 = fmaf(f0.z, w1, a2); a3 = fmaf(f0.w, w1, a3);
        b0 = fmaf(f1.x, w0, b0); b1 = fmaf(f1.y, w1, b1);
        b2 = fmaf(f1.z, w1, b2); b3 = fmaf(f1.w, w1, b3);
    }
    const float s = 0.08838834764831845f; // 1/sqrt(128)
    float* o = out + (size_t)n * 512;
    o[k] = a0 * s;
    o[128 + 3 * k + 0] = a1 * s;
    o[128 + 3 * k + 1] = a2 * s;
    o[128 + 3 * k + 2] = a3 * s;
    o += 512;
    o[k] = b0 * s;
    o[128 + 3 * k + 0] = b1 * s;
    o[128 + 3 * k + 1] = b2 * s;
    o[128 + 3 * k + 2] = b3 * s;
}

extern "C" void kernel_launch(void* const* d_in, const int* in_sizes, int n_in,
                              void* d_out, int out_size, void* d_ws, size_t ws_size,
                              hipStream_t stream) {
    const float* x     = (const float*)d_in[0];
    const int*   spec  = (const int*)d_in[1];
    const float* U1_0  = (const float*)d_in[2];
    const float* U2_0  = (const float*)d_in[3];
    const float* U3_0  = (const float*)d_in[4];
    const float* W1_0  = (const float*)d_in[5];
    const float* W2_0  = (const float*)d_in[6];
    const float* W3_0  = (const float*)d_in[7];
    const float* Wl_0  = (const float*)d_in[8];
    const float* U1_1  = (const float*)d_in[9];
    const float* U2_1  = (const float*)d_in[10];
    const float* U3_1  = (const float*)d_in[11];
    const float* W1_1  = (const float*)d_in[12];
    const float* W2_1  = (const float*)d_in[13];
    const float* W3_1  = (const float*)d_in[14];
    const float* Wl_1  = (const float*)d_in[15];

    char* ws = (char*)d_ws;
    int*    nodelist = (int*)(ws + NL_OFF);
    int*    counts   = (int*)(ws + CNT_OFF);
    uint2*  call4h   = (uint2*)(ws + CALL_OFF);
    __half* uhat     = (__half*)(ws + UHAT_OFF);
    float4* fbuf     = (float4*)(ws + F_OFF);

    k_setup<<<dim3(70), dim3(256), 0, stream>>>(U3_0, U3_1, U2_0, U2_1, U1_0, U1_1,
                                                spec, uhat, nodelist, counts);
    k_fold<<<dim3(880), dim3(256), 0, stream>>>(uhat, W1_0, W2_0, W3_0,
                                                W1_1, W2_1, W3_1, call4h);
    k_eval<<<dim3(640), dim3(256), 0, stream>>>(x, nodelist, counts, call4h, fbuf);
    k_linear<<<dim3(256), dim3(256), 0, stream>>>(fbuf, Wl_0, Wl_1, (float*)d_out);
}